// Round 9
// baseline (101.141 us; speedup 1.0000x reference)
//
#include <hip/hip_runtime.h>

// Problem constants (from reference):
//   input_ids: [32,128,32] int32  -> 4096 output rows, 32 words each
//   table:     [32000,256] f32
//   gamma,beta:[256] f32
//   out:       [32,128,256] f32
#define N_ROWS 4096   // B*S = 32*128
#define W      32
#define DIM    256
#define TE_EPS 1e-12f

// One wave (64 lanes) per output (b,s) row; each lane owns 4 dims (float4).
// 4 waves per 256-thread block -> 1024 blocks.
__global__ __launch_bounds__(256) void te_kernel(
    const int*   __restrict__ ids,
    const float* __restrict__ table,
    const float* __restrict__ gamma,
    const float* __restrict__ beta,
    float*       __restrict__ out)
{
    const int wave = (blockIdx.x * blockDim.x + threadIdx.x) >> 6;   // 0..4095
    const int lane = threadIdx.x & 63;

    // Each lane's 4 dims
    const float4 g = *reinterpret_cast<const float4*>(gamma + lane * 4);
    const float4 b = *reinterpret_cast<const float4*>(beta  + lane * 4);

    // Preload this row's 32 word indices (lanes 0..31 and 32..63 duplicate).
    const int myidx = ids[wave * W + (lane & 31)];

    float4 acc = make_float4(0.f, 0.f, 0.f, 0.f);

    #pragma unroll 4
    for (int w = 0; w < W; ++w) {
        const int id = __shfl(myidx, w);   // broadcast word w's index (64-wide)
        const float4 v = *reinterpret_cast<const float4*>(
            table + (size_t)id * DIM + lane * 4);

        float s  = v.x + v.y + v.z + v.w;
        float sq = v.x * v.x + v.y * v.y + v.z * v.z + v.w * v.w;
        // 64-lane butterfly reduce of (s, sq)
        #pragma unroll
        for (int off = 32; off > 0; off >>= 1) {
            s  += __shfl_xor(s,  off);
            sq += __shfl_xor(sq, off);
        }
        const float mu  = s * (1.0f / 256.0f);
        const float var = sq * (1.0f / 256.0f) - mu * mu;
        const float rs  = rsqrtf(var + TE_EPS);

        acc.x += (v.x - mu) * rs;
        acc.y += (v.y - mu) * rs;
        acc.z += (v.z - mu) * rs;
        acc.w += (v.w - mu) * rs;
    }

    // gamma/beta distribute over the word-sum: sum(g*n + b) = g*sum(n) + W*b
    float4 o;
    o.x = acc.x * g.x + (float)W * b.x;
    o.y = acc.y * g.y + (float)W * b.y;
    o.z = acc.z * g.z + (float)W * b.z;
    o.w = acc.w * g.w + (float)W * b.w;

    *reinterpret_cast<float4*>(out + (size_t)wave * DIM + lane * 4) = o;
}

extern "C" void kernel_launch(void* const* d_in, const int* in_sizes, int n_in,
                              void* d_out, int out_size, void* d_ws, size_t ws_size,
                              hipStream_t stream) {
    const int*   ids   = (const int*)  d_in[0];
    const float* table = (const float*)d_in[1];
    const float* gamma = (const float*)d_in[2];
    const float* beta  = (const float*)d_in[3];
    float*       out   = (float*)      d_out;

    // 4096 waves, 4 waves per block -> 1024 blocks of 256 threads
    te_kernel<<<N_ROWS / 4, 256, 0, stream>>>(ids, table, gamma, beta, out);
}

// Round 11
// 96.997 us; speedup vs baseline: 1.0427x; 1.0427x over previous
//
#include <hip/hip_runtime.h>

// Problem constants (from reference):
//   input_ids: [32,128,32] int32  -> 4096 output rows, 32 words each
//   table:     [32000,256] f32
//   gamma,beta:[256] f32
//   out:       [32,128,256] f32
#define N_ROWS 4096   // B*S = 32*128
#define W      32
#define DIM    256
#define TE_EPS 1e-12f

// One block (4 waves) per output row. Each wave handles 8 of the 32 words
// (serial chain 8 deep instead of 32), lanes own 4 dims each (float4).
// Partials combine via LDS; wave 0 applies gamma/beta and stores.
__global__ __launch_bounds__(256) void te_kernel(
    const int*   __restrict__ ids,
    const float* __restrict__ table,
    const float* __restrict__ gamma,
    const float* __restrict__ beta,
    float*       __restrict__ out)
{
    const int row  = blockIdx.x;        // 0..4095
    const int tid  = threadIdx.x;
    const int wv   = tid >> 6;          // sub-wave 0..3
    const int lane = tid & 63;

    __shared__ float4 part[3][64];      // waves 1..3 deposit partial sums

    // Wave wv owns words [wv*8, wv*8+8). Lanes 0..7 preload the 8 indices
    // (other lanes load duplicates; broadcast below reads lanes 0..7).
    const int myidx = ids[row * W + wv * 8 + (lane & 7)];

    float4 acc = make_float4(0.f, 0.f, 0.f, 0.f);

    #pragma unroll
    for (int w = 0; w < 8; ++w) {
        const int id = __shfl(myidx, w);   // lane w holds this wave's word w
        const float4 v = *reinterpret_cast<const float4*>(
            table + (size_t)id * DIM + lane * 4);

        float s  = v.x + v.y + v.z + v.w;
        float sq = v.x * v.x + v.y * v.y + v.z * v.z + v.w * v.w;
        // 64-lane butterfly reduce of (s, sq) — two independent chains
        #pragma unroll
        for (int off = 32; off > 0; off >>= 1) {
            s  += __shfl_xor(s,  off);
            sq += __shfl_xor(sq, off);
        }
        const float mu  = s * (1.0f / 256.0f);
        const float var = sq * (1.0f / 256.0f) - mu * mu;
        const float rs  = rsqrtf(var + TE_EPS);

        acc.x += (v.x - mu) * rs;
        acc.y += (v.y - mu) * rs;
        acc.z += (v.z - mu) * rs;
        acc.w += (v.w - mu) * rs;
    }

    if (wv != 0) {
        part[wv - 1][lane] = acc;          // contiguous ds_write_b128, conflict-free
    }
    __syncthreads();

    if (wv == 0) {
        const float4 a1 = part[0][lane];
        const float4 a2 = part[1][lane];
        const float4 a3 = part[2][lane];
        acc.x += a1.x + a2.x + a3.x;
        acc.y += a1.y + a2.y + a3.y;
        acc.z += a1.z + a2.z + a3.z;
        acc.w += a1.w + a2.w + a3.w;

        const float4 g = *reinterpret_cast<const float4*>(gamma + lane * 4);
        const float4 b = *reinterpret_cast<const float4*>(beta  + lane * 4);

        // gamma/beta distribute over the word-sum: sum(g*n + b) = g*sum(n) + W*b
        float4 o;
        o.x = acc.x * g.x + (float)W * b.x;
        o.y = acc.y * g.y + (float)W * b.y;
        o.z = acc.z * g.z + (float)W * b.z;
        o.w = acc.w * g.w + (float)W * b.w;

        *reinterpret_cast<float4*>(out + (size_t)row * DIM + lane * 4) = o;
    }
}

extern "C" void kernel_launch(void* const* d_in, const int* in_sizes, int n_in,
                              void* d_out, int out_size, void* d_ws, size_t ws_size,
                              hipStream_t stream) {
    const int*   ids   = (const int*)  d_in[0];
    const float* table = (const float*)d_in[1];
    const float* gamma = (const float*)d_in[2];
    const float* beta  = (const float*)d_in[3];
    float*       out   = (float*)      d_out;

    // One block per row: 4096 blocks of 256 threads (4 waves, 8 words each)
    te_kernel<<<N_ROWS, 256, 0, stream>>>(ids, table, gamma, beta, out);
}